// Round 19
// baseline (311.409 us; speedup 1.0000x reference)
//
#include <hip/hip_runtime.h>
#include <math.h>

#define Bb 64
#define N0 1024
#define NE 16384
#define Fd 128
#define K1 512
#define K2 256
#define RPB 256  // rows per k_graph block

typedef __attribute__((ext_vector_type(8))) short short8v;
typedef __attribute__((ext_vector_type(4))) float float4v;

__device__ __forceinline__ float wred_sum(float v) {
#pragma unroll
  for (int o = 32; o > 0; o >>= 1) v += __shfl_down(v, o, 64);
  return v;
}
__device__ __forceinline__ float wred_sum_all(float v) {
#pragma unroll
  for (int o = 32; o > 0; o >>= 1) v += __shfl_xor(v, o, 64);
  return v;
}
__device__ __forceinline__ float wred_max_all(float v) {
#pragma unroll
  for (int o = 32; o > 0; o >>= 1) v = fmaxf(v, __shfl_xor(v, o, 64));
  return v;
}
__device__ __forceinline__ unsigned short bf16hi(float x) {
  unsigned u = __float_as_uint(x);
  return (unsigned short)((u + 0x7fffu + ((u >> 16) & 1u)) >> 16);
}
__device__ __forceinline__ float bf2f(unsigned short h) {
  return __uint_as_float(((unsigned)h) << 16);
}

// ---- fused graph build: edges -> LDS bitmask -> adj + degree + nbr list ----
// nbr entries are PRE-SWIZZLED: s = (j<<2)|(j&3); consumer addr = (s^c4)<<4 bytes.
__global__ __launch_bounds__(1024) void k_graph(const int* __restrict__ src,
    const int* __restrict__ dst, unsigned* __restrict__ adj,
    unsigned short* __restrict__ nbr, int* __restrict__ degv,
    float* __restrict__ dis0, float* __restrict__ dis1) {
  __shared__ unsigned lmask[RPB * 32];  // 32 KB
  int t = threadIdx.x;
  int b = blockIdx.x >> 2;
  int rlo = (blockIdx.x & 3) * RPB;
#pragma unroll
  for (int i = t; i < RPB * 32; i += 1024) lmask[i] = 0;
  __syncthreads();
  const int* sp = src + b * NE;
  const int* dp = dst + b * NE;
#pragma unroll
  for (int e = t; e < NE; e += 1024) {
    int u = sp[e], v = dp[e];
    if (u == v) continue;
    if ((unsigned)(u - rlo) < RPB)
      atomicOr(&lmask[(u - rlo) * 32 + (v >> 5)], 1u << (v & 31));
    if ((unsigned)(v - rlo) < RPB)
      atomicOr(&lmask[(v - rlo) * 32 + (u >> 5)], 1u << (u & 31));
  }
  __syncthreads();
  unsigned* adjg = adj + ((size_t)(b << 10) + rlo) * 32;
#pragma unroll
  for (int i = t; i < RPB * 32; i += 1024) adjg[i] = lmask[i];
  if (t < RPB) {
    int row = (b << 10) + rlo + t;
    const unsigned* wm = &lmask[t * 32];
    int d = 0;
#pragma unroll
    for (int i = 0; i < 32; ++i) d += __popc(wm[i]);
    degv[row] = d;
    dis0[row] = d > 0 ? rsqrtf((float)d) : 0.f;
    dis1[row] = rsqrtf((float)(d + 1));
    unsigned short* dstp = nbr + (size_t)row * 128;
    int o = 0;
#pragma unroll
    for (int w = 0; w < 32; ++w) {
      unsigned m = wm[w];
      int bas = w << 5;
      while (m) {
        int j = bas + __ffs(m) - 1; m &= m - 1;
        dstp[o++] = (unsigned short)((j << 2) | (j & 3));
      }
    }
  }
}

// ---- C[M,128] = X[M,128] @ W[128,128] via 3xbf16-split MFMA ----
__global__ __launch_bounds__(512) void k_gemmm(const float* __restrict__ X,
                                               const float* __restrict__ W,
                                               float* __restrict__ C) {
  __shared__ unsigned short AsHi[64 * 40], AsLo[64 * 40];     // 10 KB
  __shared__ unsigned short YtHi[128 * 40], YtLo[128 * 40];   // 20 KB
  int t = threadIdx.x;
  size_t row0 = (size_t)blockIdx.x * 64;
  const float* Xb = X + row0 * Fd;
  int sar = t >> 3, sak = (t & 7) << 2;
  int awoff = sar * 40 + ((sak >> 3) ^ ((sar >> 3) & 3)) * 8 + (sak & 4);
  int wc = t & 127, ob = t >> 7;  // W staging: col, k-octet
  int ywoff = wc * 40 + (ob ^ ((wc >> 3) & 3)) * 8;
  int w = t >> 6, l = t & 63;
  int tr = w & 3, ch = w >> 2;
  int lr = l & 15, lg4 = l >> 4;
  int arow = 16 * tr + lr;
  int aroff = arow * 40 + ((lg4 ^ ((arow >> 3) & 3)) << 3);
  int boff[4];
#pragma unroll
  for (int j = 0; j < 4; ++j) {
    int colj = ch * 64 + j * 16 + lr;
    boff[j] = colj * 40 + ((lg4 ^ ((colj >> 3) & 3)) << 3);
  }
  float4v acc[4] = {{0.f, 0.f, 0.f, 0.f}, {0.f, 0.f, 0.f, 0.f},
                    {0.f, 0.f, 0.f, 0.f}, {0.f, 0.f, 0.f, 0.f}};
  for (int kb = 0; kb < 128; kb += 32) {
    __syncthreads();
    {  // stage X tile hi/lo
      float4 av = *(const float4*)&Xb[(size_t)sar * Fd + kb + sak];
      float vs[4] = {av.x, av.y, av.z, av.w};
      unsigned short h[4], lo[4];
#pragma unroll
      for (int i = 0; i < 4; ++i) {
        h[i] = bf16hi(vs[i]);
        float fhi = __uint_as_float(((unsigned)h[i]) << 16);
        lo[i] = bf16hi(vs[i] - fhi);
      }
      uint2 ph, pl;
      ph.x = (unsigned)h[0] | ((unsigned)h[1] << 16);
      ph.y = (unsigned)h[2] | ((unsigned)h[3] << 16);
      pl.x = (unsigned)lo[0] | ((unsigned)lo[1] << 16);
      pl.y = (unsigned)lo[2] | ((unsigned)lo[3] << 16);
      *(uint2*)&AsHi[awoff] = ph;
      *(uint2*)&AsLo[awoff] = pl;
    }
    {  // stage Wt hi/lo col-strips (b128 writes)
      float vs[8];
      const float* wp = W + (size_t)(kb + ob * 8) * Fd + wc;
#pragma unroll
      for (int kk = 0; kk < 8; ++kk) vs[kk] = wp[(size_t)kk * Fd];
      uint4 uh, ul;
      unsigned hu[4], lu[4];
#pragma unroll
      for (int kk = 0; kk < 4; ++kk) {
        unsigned short h0 = bf16hi(vs[2 * kk]);
        unsigned short l0 = bf16hi(vs[2 * kk] - __uint_as_float(((unsigned)h0) << 16));
        unsigned short h1 = bf16hi(vs[2 * kk + 1]);
        unsigned short l1 = bf16hi(vs[2 * kk + 1] - __uint_as_float(((unsigned)h1) << 16));
        hu[kk] = (unsigned)h0 | ((unsigned)h1 << 16);
        lu[kk] = (unsigned)l0 | ((unsigned)l1 << 16);
      }
      uh.x = hu[0]; uh.y = hu[1]; uh.z = hu[2]; uh.w = hu[3];
      ul.x = lu[0]; ul.y = lu[1]; ul.z = lu[2]; ul.w = lu[3];
      *(uint4*)&YtHi[ywoff] = uh;
      *(uint4*)&YtLo[ywoff] = ul;
    }
    __syncthreads();
    short8v ah = *(const short8v*)&AsHi[aroff];
    short8v al = *(const short8v*)&AsLo[aroff];
#pragma unroll
    for (int j = 0; j < 4; ++j) {
      short8v bh = *(const short8v*)&YtHi[boff[j]];
      short8v bl = *(const short8v*)&YtLo[boff[j]];
      acc[j] = __builtin_amdgcn_mfma_f32_16x16x32_bf16(ah, bh, acc[j], 0, 0, 0);
      acc[j] = __builtin_amdgcn_mfma_f32_16x16x32_bf16(ah, bl, acc[j], 0, 0, 0);
      acc[j] = __builtin_amdgcn_mfma_f32_16x16x32_bf16(al, bh, acc[j], 0, 0, 0);
    }
  }
#pragma unroll
  for (int r = 0; r < 4; ++r) {
    size_t grow = row0 + 16 * tr + (lg4 << 2) + r;
#pragma unroll
    for (int j = 0; j < 4; ++j) {
      int gcol = ch * 64 + j * 16 + lr;
      C[grow * Fd + gcol] = acc[j][r];
    }
  }
}

// ---- fused conv1 + NIS via LDS-staged source, pre-swizzled offsets ----
__global__ __launch_bounds__(1024) void k_convnis(const unsigned short* __restrict__ nbr,
    const int* __restrict__ degv, const float* __restrict__ XW,
    const float* __restrict__ dis0, const float* __restrict__ dis1,
    const float* __restrict__ b1, float* __restrict__ h1, float* __restrict__ partial) {
  __shared__ float Xs[N0 * 16];  // 64 KB
  int t = threadIdx.x;
  int g = blockIdx.x & 63;
  int cb = blockIdx.x >> 6;
  int c16 = cb * 16;
  const float* XWg = XW + ((size_t)(g << 10)) * Fd + c16;
  const float* d1g = dis1 + (g << 10);
  const float* d0g = dis0 + (g << 10);
  {
    int r = t;
    float s = d1g[r];
    int sw = r & 3;
#pragma unroll
    for (int sl = 0; sl < 4; ++sl) {
      int lc = sl ^ sw;
      float4 v = *(const float4*)&XWg[(size_t)r * Fd + lc * 4];
      v.x *= s; v.y *= s; v.z *= s; v.w *= s;
      *(float4*)&Xs[r * 16 + sl * 4] = v;
    }
  }
  __syncthreads();
  int c4 = t & 3, rsl = t >> 2;
  const unsigned short* nb = nbr + (((size_t)(g << 10)) << 7);
  float4 bv = *(const float4*)&b1[c16 + c4 * 4];
  float4 hsave[4];
  int degs[4];
  const char* Xb = (const char*)Xs;
  int cx = c4 << 4;  // XOR constant in byte space
#pragma unroll
  for (int rg = 0; rg < 4; ++rg) {
    int lrow = rg * 256 + rsl;
    int grow = (g << 10) + lrow;
    int deg = degv[grow];
    degs[rg] = deg;
    const unsigned short* nr = nb + ((size_t)lrow << 7);
    float4 acc = make_float4(0.f, 0.f, 0.f, 0.f);
    int dp = deg & ~7, i = 0;
    for (; i < dp; i += 8) {
      uint4 w = *(const uint4*)&nr[i];
      int s_[8] = {(int)(w.x & 0xffffu), (int)(w.x >> 16),
                   (int)(w.y & 0xffffu), (int)(w.y >> 16),
                   (int)(w.z & 0xffffu), (int)(w.z >> 16),
                   (int)(w.w & 0xffffu), (int)(w.w >> 16)};
      float4 vv[8];
#pragma unroll
      for (int u = 0; u < 8; ++u)
        vv[u] = *(const float4*)(Xb + ((s_[u] << 4) ^ cx));
#pragma unroll
      for (int u = 0; u < 8; ++u) {
        acc.x += vv[u].x; acc.y += vv[u].y; acc.z += vv[u].z; acc.w += vv[u].w;
      }
    }
    for (; i < deg; ++i) {
      int s = nr[i];
      float4 v = *(const float4*)(Xb + ((s << 4) ^ cx));
      acc.x += v.x; acc.y += v.y; acc.z += v.z; acc.w += v.w;
    }
    float di = d1g[lrow];
    int sself = (lrow << 2) | (lrow & 3);
    float4 self = *(const float4*)(Xb + ((sself << 4) ^ cx));
    float4 h;
    h.x = fmaxf(di * (acc.x + self.x) + bv.x, 0.f);
    h.y = fmaxf(di * (acc.y + self.y) + bv.y, 0.f);
    h.z = fmaxf(di * (acc.z + self.z) + bv.z, 0.f);
    h.w = fmaxf(di * (acc.w + self.w) + bv.w, 0.f);
    hsave[rg] = h;
    *(float4*)&h1[(size_t)grow * Fd + c16 + c4 * 4] = h;
  }
  __syncthreads();
#pragma unroll
  for (int rg = 0; rg < 4; ++rg) {
    int lrow = rg * 256 + rsl;
    float s0 = d0g[lrow];
    float4 h = hsave[rg];
    h.x *= s0; h.y *= s0; h.z *= s0; h.w *= s0;
    int sself = (lrow << 2) | (lrow & 3);
    *(float4*)((char*)Xs + ((sself << 4) ^ cx)) = h;
  }
  __syncthreads();
#pragma unroll
  for (int rg = 0; rg < 4; ++rg) {
    int lrow = rg * 256 + rsl;
    int grow = (g << 10) + lrow;
    int deg = degs[rg];
    const unsigned short* nr = nb + ((size_t)lrow << 7);
    float4 acc = make_float4(0.f, 0.f, 0.f, 0.f);
    int dp = deg & ~7, i = 0;
    for (; i < dp; i += 8) {
      uint4 w = *(const uint4*)&nr[i];
      int s_[8] = {(int)(w.x & 0xffffu), (int)(w.x >> 16),
                   (int)(w.y & 0xffffu), (int)(w.y >> 16),
                   (int)(w.z & 0xffffu), (int)(w.z >> 16),
                   (int)(w.w & 0xffffu), (int)(w.w >> 16)};
      float4 vv[8];
#pragma unroll
      for (int u = 0; u < 8; ++u)
        vv[u] = *(const float4*)(Xb + ((s_[u] << 4) ^ cx));
#pragma unroll
      for (int u = 0; u < 8; ++u) {
        acc.x += vv[u].x; acc.y += vv[u].y; acc.z += vv[u].z; acc.w += vv[u].w;
      }
    }
    for (; i < deg; ++i) {
      int s = nr[i];
      float4 v = *(const float4*)(Xb + ((s << 4) ^ cx));
      acc.x += v.x; acc.y += v.y; acc.z += v.z; acc.w += v.w;
    }
    float d0 = d0g[lrow];
    float4 h = hsave[rg];
    float p = fabsf(h.x - d0 * acc.x) + fabsf(h.y - d0 * acc.y) +
              fabsf(h.z - d0 * acc.z) + fabsf(h.w - d0 * acc.w);
    p += __shfl_xor(p, 1, 64);
    p += __shfl_xor(p, 2, 64);
    if (c4 == 0) partial[(size_t)grow * 8 + cb] = p;
  }
}

// ---- exact top-k per graph; hybrid bitonic: j<=32 in-wave via shfl, j>=64 LDS ----
__global__ __launch_bounds__(1024) void k_topk(const float* __restrict__ score,
                                               int* __restrict__ perm, int n, int k,
                                               int ps) {
  __shared__ unsigned long long keys[1024];
  int b = blockIdx.x, t = threadIdx.x;
  float s = 0.f;
  const float* p = score + ((size_t)b * n + t) * ps;
  for (int i = 0; i < ps; ++i) s += p[i];
  unsigned ub = __float_as_uint(s);
  unsigned su = (ub & 0x80000000u) ? ~ub : (ub | 0x80000000u);  // monotone map
  unsigned long long mykey = ((unsigned long long)(~su) << 32) | (unsigned)t;
  for (int kk = 2; kk <= n; kk <<= 1) {
    for (int j = kk >> 1; j > 0; j >>= 1) {
      unsigned long long other;
      if (j >= 64) {
        keys[t] = mykey;
        __syncthreads();
        other = keys[t ^ j];
        __syncthreads();
      } else {
        other = __shfl_xor(mykey, j, 64);
      }
      bool asc = ((t & kk) == 0);
      bool lower = ((t & j) == 0);
      bool keepmin = (asc == lower);
      bool takeOther = keepmin ? (other < mykey) : (other > mykey);
      if (takeOther) mykey = other;
    }
  }
  if (t < k) perm[b * k + t] = (int)(mykey & 0xffffffffu);
}

// ---- gather pooled rows + attention dots ----
__global__ __launch_bounds__(128) void k_gather(const float* __restrict__ h,
    const int* __restrict__ perm, const float* __restrict__ att, float* __restrict__ Xp,
    float* __restrict__ ar, float* __restrict__ ac, int n, int k) {
  int idx = blockIdx.x, f = threadIdx.x;
  int b = idx / k;
  __shared__ float red[4];
  int p = perm[idx];
  float v = h[((size_t)b * n + p) * Fd + f];
  Xp[(size_t)idx * Fd + f] = v;
  float r1 = wred_sum(v * att[f]);
  float r2 = wred_sum(v * att[Fd + f]);
  if ((f & 63) == 0) { red[f >> 6] = r1; red[2 + (f >> 6)] = r2; }
  __syncthreads();
  if (f == 0) { ar[idx] = red[0] + red[1]; ac[idx] = red[2] + red[3]; }
}

// ---- readout: g[b][0:128] (+)= relu(max), g[b][128:256] (+)= relu(mean) ----
__global__ __launch_bounds__(1024) void k_readout(const float* __restrict__ X, int n,
                                                  float* __restrict__ g, int init) {
  int b = blockIdx.x, t = threadIdx.x;
  int f = t & 127, rs = t >> 7;
  __shared__ float smax[8][128];
  __shared__ float ssum[8][128];
  int per = n >> 3;
  const float* Xs = X + ((size_t)b * n + (size_t)rs * per) * Fd + f;
  float mx = -3.0e38f, sm = 0.f;
  for (int j = 0; j < per; j += 8) {
    float vv[8];
#pragma unroll
    for (int u = 0; u < 8; ++u) vv[u] = Xs[(size_t)(j + u) * Fd];
#pragma unroll
    for (int u = 0; u < 8; ++u) { mx = fmaxf(mx, vv[u]); sm += vv[u]; }
  }
  smax[rs][f] = mx; ssum[rs][f] = sm;
  __syncthreads();
  if (t < 128) {
    float m = smax[0][f], s = ssum[0][f];
#pragma unroll
    for (int q = 1; q < 8; ++q) { m = fmaxf(m, smax[q][f]); s += ssum[q][f]; }
    float a = fmaxf(m, 0.f);
    float m2 = fmaxf(s / (float)n, 0.f);
    if (init) { g[b * 384 + f] = a; g[b * 384 + 128 + f] = m2; }
    else      { g[b * 384 + f] += a; g[b * 384 + 128 + f] += m2; }
  }
}

// ---- A1 = softmax_row(leakyrelu(ar_i+ac_j) + bit(pi,pj)) + row stats ----
// Writes A as bf16 hi/lo planes (consumed conversion-free by k_mmf).
__global__ __launch_bounds__(256) void k_buildA_bit(const unsigned* __restrict__ adj,
    const int* __restrict__ perm, const float* __restrict__ ar, const float* __restrict__ ac,
    unsigned short* __restrict__ Ahi, unsigned short* __restrict__ Alo,
    float* __restrict__ disc, float* __restrict__ saO,
    float* __restrict__ disn, float* __restrict__ diagO) {
  int wid = threadIdx.x >> 6, lane = threadIdx.x & 63;
  int row = blockIdx.x * 4 + wid;      // [0, Bb*K1)
  int b = row >> 9, i = row & (K1 - 1);
  int pbase = b << 9;
  int pi = perm[pbase + i];
  float ari = ar[pbase + i];
  int j0 = lane * 8;
  float acv[8]; int pj[8];
  *(float4*)&acv[0] = *(const float4*)&ac[pbase + j0];
  *(float4*)&acv[4] = *(const float4*)&ac[pbase + j0 + 4];
  *(int4*)&pj[0] = *(const int4*)&perm[pbase + j0];
  *(int4*)&pj[4] = *(const int4*)&perm[pbase + j0 + 4];
  const unsigned* arow = adj + (size_t)((b << 10) + pi) * 32;
  float xv[8];
#pragma unroll
  for (int u = 0; u < 8; ++u) {
    float x = ari + acv[u];
    x = x > 0.f ? x : 0.2f * x;
    unsigned word = arow[pj[u] >> 5];
    xv[u] = x + (float)((word >> (pj[u] & 31)) & 1u);
  }
  float m = xv[0];
#pragma unroll
  for (int u = 1; u < 8; ++u) m = fmaxf(m, xv[u]);
  m = wred_max_all(m);
  float e[8], ls = 0.f;
#pragma unroll
  for (int u = 0; u < 8; ++u) { e[u] = expf(xv[u] - m); ls += e[u]; }
  float s = wred_sum_all(ls);
  float inv = 1.0f / s;
  float av[8]; float lsum = 0.f;
#pragma unroll
  for (int u = 0; u < 8; ++u) { av[u] = e[u] * inv; lsum += av[u]; }
  unsigned short hi[8], lo[8];
#pragma unroll
  for (int u = 0; u < 8; ++u) {
    hi[u] = bf16hi(av[u]);
    lo[u] = bf16hi(av[u] - bf2f(hi[u]));
  }
  uint4 ph, pl;
  ph.x = (unsigned)hi[0] | ((unsigned)hi[1] << 16);
  ph.y = (unsigned)hi[2] | ((unsigned)hi[3] << 16);
  ph.z = (unsigned)hi[4] | ((unsigned)hi[5] << 16);
  ph.w = (unsigned)hi[6] | ((unsigned)hi[7] << 16);
  pl.x = (unsigned)lo[0] | ((unsigned)lo[1] << 16);
  pl.y = (unsigned)lo[2] | ((unsigned)lo[3] << 16);
  pl.z = (unsigned)lo[4] | ((unsigned)lo[5] << 16);
  pl.w = (unsigned)lo[6] | ((unsigned)lo[7] << 16);
  *(uint4*)&Ahi[(size_t)row * K1 + j0] = ph;
  *(uint4*)&Alo[(size_t)row * K1 + j0] = pl;
  float rs = wred_sum_all(lsum);
  float dsel = av[i & 7];                 // uniform index
  float dval = __shfl(dsel, i >> 3, 64);
  if (lane == 0) {
    float sav = (dval == 0.f) ? 1.f : 0.f;
    float deg = rs + sav;
    disc[row] = deg > 0.f ? rsqrtf(deg) : 0.f;
    saO[row] = sav;
    float deg0 = rs - dval;
    disn[row] = deg0 > 0.f ? rsqrtf(deg0) : 0.f;
    diagO[row] = dval;
  }
}

// ---- A2 = softmax_row(leakyrelu(ar_i+ac_j) + A1[pi,pj]) + row stats ----
__global__ __launch_bounds__(256) void k_buildA_dense(
    const unsigned short* __restrict__ AprevHi, const unsigned short* __restrict__ AprevLo,
    const int* __restrict__ perm, const float* __restrict__ ar, const float* __restrict__ ac,
    unsigned short* __restrict__ Ahi, unsigned short* __restrict__ Alo,
    float* __restrict__ disc, float* __restrict__ saO,
    float* __restrict__ disn, float* __restrict__ diagO) {
  int wid = threadIdx.x >> 6, lane = threadIdx.x & 63;
  int row = blockIdx.x * 4 + wid;      // [0, Bb*K2)
  int b = row >> 8, i = row & (K2 - 1);
  int pbase = b << 8;
  int pi = perm[pbase + i];
  float ari = ar[pbase + i];
  int j0 = lane * 4;
  float acv[4]; int pj[4];
  *(float4*)&acv[0] = *(const float4*)&ac[pbase + j0];
  *(int4*)&pj[0] = *(const int4*)&perm[pbase + j0];
  size_t apbase = (size_t)((b << 9) + pi) * K1;
  float xv[4];
#pragma unroll
  for (int u = 0; u < 4; ++u) {
    float x = ari + acv[u];
    x = x > 0.f ? x : 0.2f * x;
    float aval = bf2f(AprevHi[apbase + pj[u]]) + bf2f(AprevLo[apbase + pj[u]]);
    xv[u] = x + aval;
  }
  float m = fmaxf(fmaxf(xv[0], xv[1]), fmaxf(xv[2], xv[3]));
  m = wred_max_all(m);
  float e[4], ls = 0.f;
#pragma unroll
  for (int u = 0; u < 4; ++u) { e[u] = expf(xv[u] - m); ls += e[u]; }
  float s = wred_sum_all(ls);
  float inv = 1.0f / s;
  float av[4]; float lsum = 0.f;
#pragma unroll
  for (int u = 0; u < 4; ++u) { av[u] = e[u] * inv; lsum += av[u]; }
  unsigned short hi[4], lo[4];
#pragma unroll
  for (int u = 0; u < 4; ++u) {
    hi[u] = bf16hi(av[u]);
    lo[u] = bf16hi(av[u] - bf2f(hi[u]));
  }
  uint2 ph, pl;
  ph.x = (unsigned)hi[0] | ((unsigned)hi[1] << 16);
  ph.y = (unsigned)hi[2] | ((unsigned)hi[3] << 16);
  pl.x = (unsigned)lo[0] | ((unsigned)lo[1] << 16);
  pl.y = (unsigned)lo[2] | ((unsigned)lo[3] << 16);
  *(uint2*)&Ahi[(size_t)row * K2 + j0] = ph;
  *(uint2*)&Alo[(size_t)row * K2 + j0] = pl;
  float rs = wred_sum_all(lsum);
  float dsel = av[i & 3];
  float dval = __shfl(dsel, i >> 2, 64);
  if (lane == 0) {
    float sav = (dval == 0.f) ? 1.f : 0.f;
    float deg = rs + sav;
    disc[row] = deg > 0.f ? rsqrtf(deg) : 0.f;
    saO[row] = sav;
    float deg0 = rs - dval;
    disn[row] = deg0 > 0.f ? rsqrtf(deg0) : 0.f;
    diagO[row] = dval;
  }
}

// ---- fused dense mm via 3xbf16-split MFMA, BM=64 BN=64, full-K ----
// A pre-split bf16 hi/lo planes; register prefetch of next K-tile.
// MODE 0 (conv): h = relu(dc*(acc + sa*dc*Y) + bias)
// MODE 1 (nis):  score2[row*2+ct] = col-tile partial of sum |hv - dn*(acc - diag*dn*hv)|
template <int MODE>
__global__ __launch_bounds__(512) void k_mmf(
    const unsigned short* __restrict__ Ahi, const unsigned short* __restrict__ Alo,
    const float* __restrict__ Y, const float* __restrict__ wrow,
    const float* __restrict__ aux, const float* __restrict__ bias,
    float* __restrict__ outp, int n) {
  __shared__ unsigned short AsHi[64 * 40], AsLo[64 * 40];
  __shared__ unsigned short YtHi[64 * 40], YtLo[64 * 40];
  int t = threadIdx.x;
  int tiles2 = (n >> 6) << 1;
  int bid = blockIdx.x;
  int c = bid & 7, q = bid >> 3;
  int g = c * 8 + q / tiles2;
  int rem = q % tiles2;
  int rt = rem >> 1, ct = rem & 1;
  const unsigned short* AbHi = Ahi + (size_t)g * n * n + (size_t)(rt * 64) * n;
  const unsigned short* AbLo = Alo + (size_t)g * n * n + (size_t)(rt * 64) * n;
  const float* Yb = Y + (size_t)g * n * Fd + ct * 64;
  const float* wb = wrow + (size_t)g * n;
  int sar = t >> 3, sak = (t & 7) << 2;
  int awoff = sar * 40 + ((sak >> 3) ^ ((sar >> 3) & 3)) * 8 + (sak & 4);
  int yc = t & 63, ykb = (t >> 6) & 3;
  int ywoff = yc * 40 + (ykb ^ ((yc >> 3) & 3)) * 8;
  int w = t >> 6, l = t & 63;
  int tr = w & 3, tcb = (w >> 2) << 1;
  int lr = l & 15, lg4 = l >> 4;
  int arow = 16 * tr + lr;
  int aroff = arow * 40 + ((lg4 ^ ((arow >> 3) & 3)) << 3);
  int col0 = 16 * tcb + lr, col1 = col0 + 16;
  int b0off = col0 * 40 + ((lg4 ^ ((col0 >> 3) & 3)) << 3);
  int b1off = col1 * 40 + ((lg4 ^ ((col1 >> 3) & 3)) << 3);
  float4v acc0 = {0.f, 0.f, 0.f, 0.f};
  float4v acc1 = {0.f, 0.f, 0.f, 0.f};
  // prologue: load K-tile 0 into registers
  uint2 rAh = *(const uint2*)&AbHi[(size_t)sar * n + sak];
  uint2 rAl = *(const uint2*)&AbLo[(size_t)sar * n + sak];
  float rY[8];
  if (t < 256) {
    const float* yp = Yb + (size_t)(ykb * 8) * Fd + yc;
    const float* wp = wb + ykb * 8;
#pragma unroll
    for (int kk = 0; kk < 8; ++kk) rY[kk] = yp[(size_t)kk * Fd] * wp[kk];
  }
  for (int kb = 0; kb < n; kb += 32) {
    __syncthreads();
    // write current registers to LDS
    *(uint2*)&AsHi[awoff] = rAh;
    *(uint2*)&AsLo[awoff] = rAl;
    if (t < 256) {
      uint4 uh, ul;
      unsigned hu[4], lu[4];
#pragma unroll
      for (int kk = 0; kk < 4; ++kk) {
        unsigned short h0 = bf16hi(rY[2 * kk]);
        unsigned short l0 = bf16hi(rY[2 * kk] - bf2f(h0));
        unsigned short h1 = bf16hi(rY[2 * kk + 1]);
        unsigned short l1 = bf16hi(rY[2 * kk + 1] - bf2f(h1));
        hu[kk] = (unsigned)h0 | ((unsigned)h1 << 16);
        lu[kk] = (unsigned)l0 | ((unsigned)l1 << 16);
      }
      uh.x = hu[0]; uh.y = hu[1]; uh.z = hu[2]; uh.w = hu[3];
      ul.x = lu[0]; ul.y = lu[1]; ul.z = lu[2]; ul.w = lu[3];
      *(uint4*)&YtHi[ywoff] = uh;
      *(uint4*)&YtLo[ywoff] = ul;
    }
    // prefetch next K-tile into registers (overlaps MFMA below)
    if (kb + 32 < n) {
      rAh = *(const uint2*)&AbHi[(size_t)sar * n + kb + 32 + sak];
      rAl = *(const uint2*)&AbLo[(size_t)sar * n + kb + 32 + sak];
      if (t < 256) {
        const float* yp = Yb + (size_t)(kb + 32 + ykb * 8) * Fd + yc;
        const float* wp = wb + kb + 32 + ykb * 8;
#pragma unroll
        for (int kk = 0; kk < 8; ++kk) rY[kk] = yp[(size_t)kk * Fd] * wp[kk];
      }
    }
    __syncthreads();
    short8v ah = *(const short8v*)&AsHi[aroff];
    short8v al = *(const short8v*)&AsLo[aroff];
    short8v bh0 = *(const short8v*)&YtHi[b0off];
    short8v bl0 = *(const short8v*)&YtLo[b0off];
    short8v bh1 = *(const short8v*)&YtHi[b1off];
    short8v bl1 = *(const short8v*)&YtLo[b1off];
    acc0 = __builtin_amdgcn_mfma_f32_16x16x32_bf16(ah, bh0, acc0, 0, 0, 0);
    acc0 = __builtin_amdgcn_mfma_f32_16x16x32_bf16(ah, bl0, acc0, 0, 0, 0);
    acc0 = __builtin_amdgcn_mfma_f32_16x16x32_bf16(al, bh0, acc0, 0, 0, 0);
    acc1 = __builtin_amdgcn_mfma_f32_16x16x32_bf16(ah, bh1, acc1, 0, 0, 0);
    acc1 = __builtin_amdgcn_mfma_f32_16x16x32_bf16(ah, bl1, acc1, 0, 0, 0);
    acc1 = __builtin_amdgcn_mfma_f32_16x16x32_bf16(al, bh1, acc1, 0, 0, 0);
  }
  // epilogue: lane l holds D[row=(l>>4)*4+r][col=lr] of each tile
  int colg0 = ct * 64 + 16 * tcb + lr;
  int colg1 = colg0 + 16;
  if (MODE == 0) {
    float bv0 = bias[colg0], bv1 = bias[colg1];
#pragma unroll
    for (int r = 0; r < 4; ++r) {
      int row = rt * 64 + 16 * tr + ((l >> 4) << 2) + r;
      size_t R = (size_t)g * n + row;
      float dc = wb[row];
      float sv = aux[R] * dc;
      float y0 = Y[R * Fd + colg0];
      float y1 = Y[R * Fd + colg1];
      float o0 = fmaxf(dc * (acc0[r] + sv * y0) + bv0, 0.f);
      float o1 = fmaxf(dc * (acc1[r] + sv * y1) + bv1, 0.f);
      outp[R * Fd + colg0] = o0;
      outp[R * Fd + colg1] = o1;
    }
  } else {
#pragma unroll
    for (int r = 0; r < 4; ++r) {
      int row = rt * 64 + 16 * tr + ((l >> 4) << 2) + r;
      size_t R = (size_t)g * n + row;
      float dn = wb[row];
      float dg = aux[R] * dn;
      float h0 = Y[R * Fd + colg0];
      float h1 = Y[R * Fd + colg1];
      float p = fabsf(h0 - dn * (acc0[r] - dg * h0)) +
                fabsf(h1 - dn * (acc1[r] - dg * h1));
      p += __shfl_xor(p, 1, 64);
      p += __shfl_xor(p, 2, 64);
      p += __shfl_xor(p, 4, 64);
      p += __shfl_xor(p, 8, 64);
      if (lr == 0) outp[R * 2 + ct] = p;
    }
  }
}

// ---- fused head: xskew + mlp1 + mlp2 + mlp3 + log_softmax ----
__global__ __launch_bounds__(128) void k_head(const float* __restrict__ gin,
    const float* __restrict__ skew, const float* __restrict__ Wsk,
    const float* __restrict__ bsk, const float* __restrict__ Wl1,
    const float* __restrict__ bl1, const float* __restrict__ Wl2,
    const float* __restrict__ bl2, const float* __restrict__ Wl3,
    const float* __restrict__ bl3, float* __restrict__ out) {
  __shared__ float gl[384];
  __shared__ float t1s[128];
  __shared__ float t2s[64];
  __shared__ float lg[10];
  int b = blockIdx.x, f = threadIdx.x;
  gl[f] = gin[b * 384 + f];
  gl[128 + f] = gin[b * 384 + 128 + f];
  float acc = bsk[f];
  for (int s = 0; s < 64; ++s) acc += skew[b * 64 + s] * Wsk[s * Fd + f];
  gl[256 + f] = fmaxf(acc, 0.f);
  __syncthreads();
  acc = bl1[f];
  for (int s = 0; s < 384; ++s) acc += gl[s] * Wl1[s * 128 + f];
  t1s[f] = fmaxf(acc, 0.f);
  __syncthreads();
  if (f < 64) {
    acc = bl2[f];
    for (int s = 0; s < 128; ++s) acc += t1s[s] * Wl2[s * 64 + f];
    t2s[f] = fmaxf(acc, 0.f);
  }
  __syncthreads();
  if (f < 10) {
    acc = bl3[f];
    for (int s = 0; s < 64; ++s) acc += t2s[s] * Wl3[s * 10 + f];
    lg[f] = acc;
  }
  __syncthreads();
  if (f == 0) {
    float m = lg[0];
    for (int c = 1; c < 10; ++c) m = fmaxf(m, lg[c]);
    float s = 0.f;
    for (int c = 0; c < 10; ++c) s += expf(lg[c] - m);
    float l = logf(s);
    for (int c = 0; c < 10; ++c) out[b * 10 + c] = lg[c] - m - l;
  }
}

extern "C" void kernel_launch(void* const* d_in, const int* in_sizes, int n_in,
                              void* d_out, int out_size, void* d_ws, size_t ws_size,
                              hipStream_t stream) {
  const float* x    = (const float*)d_in[0];
  const int*   src  = (const int*)d_in[1];
  const int*   dst  = (const int*)d_in[2];
  const float* skew = (const float*)d_in[3];
  const float* W1   = (const float*)d_in[4];
  const float* b1   = (const float*)d_in[5];
  const float* W2   = (const float*)d_in[6];
  const float* b2   = (const float*)d_in[7];
  const float* W3   = (const float*)d_in[8];
  const float* b3   = (const float*)d_in[9];
  const float* att1 = (const float*)d_in[10];
  const float* att2 = (const float*)d_in[11];
  const float* Wsk  = (const float*)d_in[12];
  const float* bsk  = (const float*)d_in[13];
  const float* Wl1  = (const float*)d_in[14];
  const float* bl1  = (const float*)d_in[15];
  const float* Wl2  = (const float*)d_in[16];
  const float* bl2  = (const float*)d_in[17];
  const float* Wl3  = (const float*)d_in[18];
  const float* bl3  = (const float*)d_in[19];
  float* out = (float*)d_out;

  char* base = (char*)d_ws;
  size_t off = 0;
  auto alloc = [&](size_t bytes) -> void* {
    void* p = base + off;
    off += (bytes + 255) & ~(size_t)255;
    return p;
  };

  unsigned* adj = (unsigned*)alloc((size_t)Bb * N0 * 32 * 4);        // 8 MB
  float* dis0 = (float*)alloc((size_t)Bb * N0 * 4);
  float* dis1 = (float*)alloc((size_t)Bb * N0 * 4);
  int*   degv = (int*)alloc((size_t)Bb * N0 * 4);
  float* bigA = (float*)alloc((size_t)64 * 1024 * 1024);             // 64 MB multi-use
  float* XW  = bigA;                                                  // [B,1024,128]
  float* h1  = bigA + (size_t)Bb * N0 * Fd;                           // [B,1024,128]
  unsigned short* A1hi = (unsigned short*)bigA;                       // 32 MB (after XW/h1 dead)
  unsigned short* A1lo = (unsigned short*)bigA + (size_t)Bb * K1 * K1;// 32 MB
  float* XW3 = bigA;                                                  // [B,256,128] (after A1 dead)
  float* h3  = bigA + (size_t)Bb * K2 * Fd;                           // [B,256,128]
  float* partial = (float*)alloc((size_t)Bb * N0 * 8 * 4);            // 2 MB; also score2
  int*   perm1 = (int*)alloc((size_t)Bb * K1 * 4);
  float* Xp1 = (float*)alloc((size_t)Bb * K1 * Fd * 4);               // later reused as A2 planes
  unsigned short* A2hi = (unsigned short*)Xp1;                        // 8 MB
  unsigned short* A2lo = (unsigned short*)Xp1 + (size_t)Bb * K2 * K2; // 8 MB
  float* ar1 = (float*)alloc((size_t)Bb * K1 * 4);
  float* ac1 = (float*)alloc((size_t)Bb * K1 * 4);
  float* disc2 = (float*)alloc((size_t)Bb * K1 * 4);
  float* sa2   = (float*)alloc((size_t)Bb * K1 * 4);
  float* disn2 = (float*)alloc((size_t)Bb * K1 * 4);
  float* diag2 = (float*)alloc((size_t)Bb * K1 * 4);
  float* XW2 = (float*)alloc((size_t)Bb * K1 * Fd * 4);               // 16 MB
  float* h2  = (float*)alloc((size_t)Bb * K1 * Fd * 4);               // 16 MB
  int*   perm2 = (int*)alloc((size_t)Bb * K2 * 4);
  float* Xp2 = (float*)alloc((size_t)Bb * K2 * Fd * 4);
  float* ar2 = (float*)alloc((size_t)Bb * K2 * 4);
  float* ac2 = (float*)alloc((size_t)Bb * K2 * 4);
  float* disc3 = (float*)alloc((size_t)Bb * K2 * 4);
  float* sa3   = (float*)alloc((size_t)Bb * K2 * 4);
  float* disn3 = (float*)alloc((size_t)Bb * K2 * 4);
  float* diag3 = (float*)alloc((size_t)Bb * K2 * 4);
  float* g  = (float*)alloc((size_t)Bb * 384 * 4);
  // nbr [B*N0][128] u16 = 16 MB; overlays XW2 (dead until stage-2 gemm)
  unsigned short* nbr = (unsigned short*)XW2;
  (void)ws_size; (void)in_sizes; (void)n_in; (void)out_size;

  // stage 1: fused graph build, MFMA gemm, fused conv+nis
  k_graph<<<Bb * 4, 1024, 0, stream>>>(src, dst, adj, nbr, degv, dis0, dis1);
  k_gemmm<<<Bb * N0 / 64, 512, 0, stream>>>(x, W1, XW);
  k_convnis<<<Bb * 8, 1024, 0, stream>>>(nbr, degv, XW, dis0, dis1, b1, h1, partial);
  k_topk<<<Bb, N0, 0, stream>>>(partial, perm1, N0, K1, 8);
  k_gather<<<Bb * K1, 128, 0, stream>>>(h1, perm1, att1, Xp1, ar1, ac1, N0, K1);
  k_readout<<<Bb, 1024, 0, stream>>>(Xp1, K1, g, 1);
  k_buildA_bit<<<Bb * K1 / 4, 256, 0, stream>>>(adj, perm1, ar1, ac1, A1hi, A1lo,
                                                disc2, sa2, disn2, diag2);  // overwrites XW/h1

  // stage 2: dense A1 (MFMA mm with pre-split A planes, reg prefetch)
  k_gemmm<<<Bb * K1 / 64, 512, 0, stream>>>(Xp1, W2, XW2);
  k_mmf<0><<<Bb * (K1 / 64) * 2, 512, 0, stream>>>(A1hi, A1lo, XW2, disc2, sa2, b2, h2, K1);
  k_mmf<1><<<Bb * (K1 / 64) * 2, 512, 0, stream>>>(A1hi, A1lo, h2, disn2, diag2, nullptr, partial, K1);
  k_topk<<<Bb, K1, 0, stream>>>(partial, perm2, K1, K2, 2);
  k_gather<<<Bb * K2, 128, 0, stream>>>(h2, perm2, att2, Xp2, ar2, ac2, K1, K2);
  k_readout<<<Bb, 1024, 0, stream>>>(Xp2, K2, g, 0);
  k_buildA_dense<<<Bb * K2 / 4, 256, 0, stream>>>(A1hi, A1lo, perm2, ar2, ac2,
                                                  A2hi, A2lo, disc3, sa3, disn3, diag3);

  // stage 3: dense A2
  k_gemmm<<<Bb * K2 / 64, 512, 0, stream>>>(Xp2, W3, XW3);             // overwrites A1 region
  k_mmf<0><<<Bb * (K2 / 64) * 2, 512, 0, stream>>>(A2hi, A2lo, XW3, disc3, sa3, b3, h3, K2);
  k_readout<<<Bb, 1024, 0, stream>>>(h3, K2, g, 0);

  // fused head
  k_head<<<Bb, 128, 0, stream>>>(g, skew, Wsk, bsk, Wl1, bl1, Wl2, bl2, Wl3, bl3, out);
}

// Round 20
// 303.481 us; speedup vs baseline: 1.0261x; 1.0261x over previous
//
#include <hip/hip_runtime.h>
#include <math.h>

#define Bb 64
#define N0 1024
#define NE 16384
#define Fd 128
#define K1 512
#define K2 256
#define RPB 256  // rows per k_graph block

typedef __attribute__((ext_vector_type(8))) short short8v;
typedef __attribute__((ext_vector_type(4))) float float4v;

__device__ __forceinline__ float wred_sum(float v) {
#pragma unroll
  for (int o = 32; o > 0; o >>= 1) v += __shfl_down(v, o, 64);
  return v;
}
__device__ __forceinline__ float wred_sum_all(float v) {
#pragma unroll
  for (int o = 32; o > 0; o >>= 1) v += __shfl_xor(v, o, 64);
  return v;
}
__device__ __forceinline__ float wred_max_all(float v) {
#pragma unroll
  for (int o = 32; o > 0; o >>= 1) v = fmaxf(v, __shfl_xor(v, o, 64));
  return v;
}
__device__ __forceinline__ unsigned short bf16hi(float x) {
  unsigned u = __float_as_uint(x);
  return (unsigned short)((u + 0x7fffu + ((u >> 16) & 1u)) >> 16);
}
__device__ __forceinline__ float bf2f(unsigned short h) {
  return __uint_as_float(((unsigned)h) << 16);
}

// ---- fused graph build: edges -> LDS bitmask -> adj + degree + nbr list ----
// nbr entries are PRE-SWIZZLED: s = (j<<2)|(j&3); consumer addr = (s^c4)<<4 bytes.
__global__ __launch_bounds__(1024) void k_graph(const int* __restrict__ src,
    const int* __restrict__ dst, unsigned* __restrict__ adj,
    unsigned short* __restrict__ nbr, int* __restrict__ degv,
    float* __restrict__ dis0, float* __restrict__ dis1) {
  __shared__ unsigned lmask[RPB * 32];  // 32 KB
  int t = threadIdx.x;
  int b = blockIdx.x >> 2;
  int rlo = (blockIdx.x & 3) * RPB;
#pragma unroll
  for (int i = t; i < RPB * 32; i += 1024) lmask[i] = 0;
  __syncthreads();
  const int* sp = src + b * NE;
  const int* dp = dst + b * NE;
#pragma unroll
  for (int e = t; e < NE; e += 1024) {
    int u = sp[e], v = dp[e];
    if (u == v) continue;
    if ((unsigned)(u - rlo) < RPB)
      atomicOr(&lmask[(u - rlo) * 32 + (v >> 5)], 1u << (v & 31));
    if ((unsigned)(v - rlo) < RPB)
      atomicOr(&lmask[(v - rlo) * 32 + (u >> 5)], 1u << (u & 31));
  }
  __syncthreads();
  unsigned* adjg = adj + ((size_t)(b << 10) + rlo) * 32;
#pragma unroll
  for (int i = t; i < RPB * 32; i += 1024) adjg[i] = lmask[i];
  if (t < RPB) {
    int row = (b << 10) + rlo + t;
    const unsigned* wm = &lmask[t * 32];
    int d = 0;
#pragma unroll
    for (int i = 0; i < 32; ++i) d += __popc(wm[i]);
    degv[row] = d;
    dis0[row] = d > 0 ? rsqrtf((float)d) : 0.f;
    dis1[row] = rsqrtf((float)(d + 1));
    unsigned short* dstp = nbr + (size_t)row * 128;
    int o = 0;
#pragma unroll
    for (int w = 0; w < 32; ++w) {
      unsigned m = wm[w];
      int bas = w << 5;
      while (m) {
        int j = bas + __ffs(m) - 1; m &= m - 1;
        dstp[o++] = (unsigned short)((j << 2) | (j & 3));
      }
    }
  }
}

// ---- C[M,128] = X[M,128] @ W[128,128] via 3xbf16-split MFMA ----
__global__ __launch_bounds__(512) void k_gemmm(const float* __restrict__ X,
                                               const float* __restrict__ W,
                                               float* __restrict__ C) {
  __shared__ unsigned short AsHi[64 * 40], AsLo[64 * 40];     // 10 KB
  __shared__ unsigned short YtHi[128 * 40], YtLo[128 * 40];   // 20 KB
  int t = threadIdx.x;
  size_t row0 = (size_t)blockIdx.x * 64;
  const float* Xb = X + row0 * Fd;
  int sar = t >> 3, sak = (t & 7) << 2;
  int awoff = sar * 40 + ((sak >> 3) ^ ((sar >> 3) & 3)) * 8 + (sak & 4);
  int wc = t & 127, ob = t >> 7;  // W staging: col, k-octet
  int ywoff = wc * 40 + (ob ^ ((wc >> 3) & 3)) * 8;
  int w = t >> 6, l = t & 63;
  int tr = w & 3, ch = w >> 2;
  int lr = l & 15, lg4 = l >> 4;
  int arow = 16 * tr + lr;
  int aroff = arow * 40 + ((lg4 ^ ((arow >> 3) & 3)) << 3);
  int boff[4];
#pragma unroll
  for (int j = 0; j < 4; ++j) {
    int colj = ch * 64 + j * 16 + lr;
    boff[j] = colj * 40 + ((lg4 ^ ((colj >> 3) & 3)) << 3);
  }
  float4v acc[4] = {{0.f, 0.f, 0.f, 0.f}, {0.f, 0.f, 0.f, 0.f},
                    {0.f, 0.f, 0.f, 0.f}, {0.f, 0.f, 0.f, 0.f}};
  for (int kb = 0; kb < 128; kb += 32) {
    __syncthreads();
    {  // stage X tile hi/lo
      float4 av = *(const float4*)&Xb[(size_t)sar * Fd + kb + sak];
      float vs[4] = {av.x, av.y, av.z, av.w};
      unsigned short h[4], lo[4];
#pragma unroll
      for (int i = 0; i < 4; ++i) {
        h[i] = bf16hi(vs[i]);
        float fhi = __uint_as_float(((unsigned)h[i]) << 16);
        lo[i] = bf16hi(vs[i] - fhi);
      }
      uint2 ph, pl;
      ph.x = (unsigned)h[0] | ((unsigned)h[1] << 16);
      ph.y = (unsigned)h[2] | ((unsigned)h[3] << 16);
      pl.x = (unsigned)lo[0] | ((unsigned)lo[1] << 16);
      pl.y = (unsigned)lo[2] | ((unsigned)lo[3] << 16);
      *(uint2*)&AsHi[awoff] = ph;
      *(uint2*)&AsLo[awoff] = pl;
    }
    {  // stage Wt hi/lo col-strips (b128 writes)
      float vs[8];
      const float* wp = W + (size_t)(kb + ob * 8) * Fd + wc;
#pragma unroll
      for (int kk = 0; kk < 8; ++kk) vs[kk] = wp[(size_t)kk * Fd];
      uint4 uh, ul;
      unsigned hu[4], lu[4];
#pragma unroll
      for (int kk = 0; kk < 4; ++kk) {
        unsigned short h0 = bf16hi(vs[2 * kk]);
        unsigned short l0 = bf16hi(vs[2 * kk] - __uint_as_float(((unsigned)h0) << 16));
        unsigned short h1 = bf16hi(vs[2 * kk + 1]);
        unsigned short l1 = bf16hi(vs[2 * kk + 1] - __uint_as_float(((unsigned)h1) << 16));
        hu[kk] = (unsigned)h0 | ((unsigned)h1 << 16);
        lu[kk] = (unsigned)l0 | ((unsigned)l1 << 16);
      }
      uh.x = hu[0]; uh.y = hu[1]; uh.z = hu[2]; uh.w = hu[3];
      ul.x = lu[0]; ul.y = lu[1]; ul.z = lu[2]; ul.w = lu[3];
      *(uint4*)&YtHi[ywoff] = uh;
      *(uint4*)&YtLo[ywoff] = ul;
    }
    __syncthreads();
    short8v ah = *(const short8v*)&AsHi[aroff];
    short8v al = *(const short8v*)&AsLo[aroff];
#pragma unroll
    for (int j = 0; j < 4; ++j) {
      short8v bh = *(const short8v*)&YtHi[boff[j]];
      short8v bl = *(const short8v*)&YtLo[boff[j]];
      acc[j] = __builtin_amdgcn_mfma_f32_16x16x32_bf16(ah, bh, acc[j], 0, 0, 0);
      acc[j] = __builtin_amdgcn_mfma_f32_16x16x32_bf16(ah, bl, acc[j], 0, 0, 0);
      acc[j] = __builtin_amdgcn_mfma_f32_16x16x32_bf16(al, bh, acc[j], 0, 0, 0);
    }
  }
#pragma unroll
  for (int r = 0; r < 4; ++r) {
    size_t grow = row0 + 16 * tr + (lg4 << 2) + r;
#pragma unroll
    for (int j = 0; j < 4; ++j) {
      int gcol = ch * 64 + j * 16 + lr;
      C[grow * Fd + gcol] = acc[j][r];
    }
  }
}

// ---- fused conv1 + NIS via LDS-staged source, pre-swizzled offsets ----
__global__ __launch_bounds__(1024) void k_convnis(const unsigned short* __restrict__ nbr,
    const int* __restrict__ degv, const float* __restrict__ XW,
    const float* __restrict__ dis0, const float* __restrict__ dis1,
    const float* __restrict__ b1, float* __restrict__ h1, float* __restrict__ partial) {
  __shared__ float Xs[N0 * 16];  // 64 KB
  int t = threadIdx.x;
  int g = blockIdx.x & 63;
  int cb = blockIdx.x >> 6;
  int c16 = cb * 16;
  const float* XWg = XW + ((size_t)(g << 10)) * Fd + c16;
  const float* d1g = dis1 + (g << 10);
  const float* d0g = dis0 + (g << 10);
  {
    int r = t;
    float s = d1g[r];
    int sw = r & 3;
#pragma unroll
    for (int sl = 0; sl < 4; ++sl) {
      int lc = sl ^ sw;
      float4 v = *(const float4*)&XWg[(size_t)r * Fd + lc * 4];
      v.x *= s; v.y *= s; v.z *= s; v.w *= s;
      *(float4*)&Xs[r * 16 + sl * 4] = v;
    }
  }
  __syncthreads();
  int c4 = t & 3, rsl = t >> 2;
  const unsigned short* nb = nbr + (((size_t)(g << 10)) << 7);
  float4 bv = *(const float4*)&b1[c16 + c4 * 4];
  float4 hsave[4];
  int degs[4];
  const char* Xb = (const char*)Xs;
  int cx = c4 << 4;  // XOR constant in byte space
#pragma unroll
  for (int rg = 0; rg < 4; ++rg) {
    int lrow = rg * 256 + rsl;
    int grow = (g << 10) + lrow;
    int deg = degv[grow];
    degs[rg] = deg;
    const unsigned short* nr = nb + ((size_t)lrow << 7);
    float4 acc = make_float4(0.f, 0.f, 0.f, 0.f);
    int dp = deg & ~7, i = 0;
    for (; i < dp; i += 8) {
      uint4 w = *(const uint4*)&nr[i];
      int s_[8] = {(int)(w.x & 0xffffu), (int)(w.x >> 16),
                   (int)(w.y & 0xffffu), (int)(w.y >> 16),
                   (int)(w.z & 0xffffu), (int)(w.z >> 16),
                   (int)(w.w & 0xffffu), (int)(w.w >> 16)};
      float4 vv[8];
#pragma unroll
      for (int u = 0; u < 8; ++u)
        vv[u] = *(const float4*)(Xb + ((s_[u] << 4) ^ cx));
#pragma unroll
      for (int u = 0; u < 8; ++u) {
        acc.x += vv[u].x; acc.y += vv[u].y; acc.z += vv[u].z; acc.w += vv[u].w;
      }
    }
    for (; i < deg; ++i) {
      int s = nr[i];
      float4 v = *(const float4*)(Xb + ((s << 4) ^ cx));
      acc.x += v.x; acc.y += v.y; acc.z += v.z; acc.w += v.w;
    }
    float di = d1g[lrow];
    int sself = (lrow << 2) | (lrow & 3);
    float4 self = *(const float4*)(Xb + ((sself << 4) ^ cx));
    float4 h;
    h.x = fmaxf(di * (acc.x + self.x) + bv.x, 0.f);
    h.y = fmaxf(di * (acc.y + self.y) + bv.y, 0.f);
    h.z = fmaxf(di * (acc.z + self.z) + bv.z, 0.f);
    h.w = fmaxf(di * (acc.w + self.w) + bv.w, 0.f);
    hsave[rg] = h;
    *(float4*)&h1[(size_t)grow * Fd + c16 + c4 * 4] = h;
  }
  __syncthreads();
#pragma unroll
  for (int rg = 0; rg < 4; ++rg) {
    int lrow = rg * 256 + rsl;
    float s0 = d0g[lrow];
    float4 h = hsave[rg];
    h.x *= s0; h.y *= s0; h.z *= s0; h.w *= s0;
    int sself = (lrow << 2) | (lrow & 3);
    *(float4*)((char*)Xs + ((sself << 4) ^ cx)) = h;
  }
  __syncthreads();
#pragma unroll
  for (int rg = 0; rg < 4; ++rg) {
    int lrow = rg * 256 + rsl;
    int grow = (g << 10) + lrow;
    int deg = degs[rg];
    const unsigned short* nr = nb + ((size_t)lrow << 7);
    float4 acc = make_float4(0.f, 0.f, 0.f, 0.f);
    int dp = deg & ~7, i = 0;
    for (; i < dp; i += 8) {
      uint4 w = *(const uint4*)&nr[i];
      int s_[8] = {(int)(w.x & 0xffffu), (int)(w.x >> 16),
                   (int)(w.y & 0xffffu), (int)(w.y >> 16),
                   (int)(w.z & 0xffffu), (int)(w.z >> 16),
                   (int)(w.w & 0xffffu), (int)(w.w >> 16)};
      float4 vv[8];
#pragma unroll
      for (int u = 0; u < 8; ++u)
        vv[u] = *(const float4*)(Xb + ((s_[u] << 4) ^ cx));
#pragma unroll
      for (int u = 0; u < 8; ++u) {
        acc.x += vv[u].x; acc.y += vv[u].y; acc.z += vv[u].z; acc.w += vv[u].w;
      }
    }
    for (; i < deg; ++i) {
      int s = nr[i];
      float4 v = *(const float4*)(Xb + ((s << 4) ^ cx));
      acc.x += v.x; acc.y += v.y; acc.z += v.z; acc.w += v.w;
    }
    float d0 = d0g[lrow];
    float4 h = hsave[rg];
    float p = fabsf(h.x - d0 * acc.x) + fabsf(h.y - d0 * acc.y) +
              fabsf(h.z - d0 * acc.z) + fabsf(h.w - d0 * acc.w);
    p += __shfl_xor(p, 1, 64);
    p += __shfl_xor(p, 2, 64);
    if (c4 == 0) partial[(size_t)grow * 8 + cb] = p;
  }
}

// ---- exact top-k per graph; hybrid bitonic: j<=32 in-wave via shfl, j>=64 LDS ----
__global__ __launch_bounds__(1024) void k_topk(const float* __restrict__ score,
                                               int* __restrict__ perm, int n, int k,
                                               int ps) {
  __shared__ unsigned long long keys[1024];
  int b = blockIdx.x, t = threadIdx.x;
  float s = 0.f;
  const float* p = score + ((size_t)b * n + t) * ps;
  for (int i = 0; i < ps; ++i) s += p[i];
  unsigned ub = __float_as_uint(s);
  unsigned su = (ub & 0x80000000u) ? ~ub : (ub | 0x80000000u);  // monotone map
  unsigned long long mykey = ((unsigned long long)(~su) << 32) | (unsigned)t;
  for (int kk = 2; kk <= n; kk <<= 1) {
    for (int j = kk >> 1; j > 0; j >>= 1) {
      unsigned long long other;
      if (j >= 64) {
        keys[t] = mykey;
        __syncthreads();
        other = keys[t ^ j];
        __syncthreads();
      } else {
        other = __shfl_xor(mykey, j, 64);
      }
      bool asc = ((t & kk) == 0);
      bool lower = ((t & j) == 0);
      bool keepmin = (asc == lower);
      bool takeOther = keepmin ? (other < mykey) : (other > mykey);
      if (takeOther) mykey = other;
    }
  }
  if (t < k) perm[b * k + t] = (int)(mykey & 0xffffffffu);
}

// ---- gather pooled rows + attention dots ----
__global__ __launch_bounds__(128) void k_gather(const float* __restrict__ h,
    const int* __restrict__ perm, const float* __restrict__ att, float* __restrict__ Xp,
    float* __restrict__ ar, float* __restrict__ ac, int n, int k) {
  int idx = blockIdx.x, f = threadIdx.x;
  int b = idx / k;
  __shared__ float red[4];
  int p = perm[idx];
  float v = h[((size_t)b * n + p) * Fd + f];
  Xp[(size_t)idx * Fd + f] = v;
  float r1 = wred_sum(v * att[f]);
  float r2 = wred_sum(v * att[Fd + f]);
  if ((f & 63) == 0) { red[f >> 6] = r1; red[2 + (f >> 6)] = r2; }
  __syncthreads();
  if (f == 0) { ar[idx] = red[0] + red[1]; ac[idx] = red[2] + red[3]; }
}

// ---- readout: g[b][0:128] (+)= relu(max), g[b][128:256] (+)= relu(mean) ----
__global__ __launch_bounds__(1024) void k_readout(const float* __restrict__ X, int n,
                                                  float* __restrict__ g, int init) {
  int b = blockIdx.x, t = threadIdx.x;
  int f = t & 127, rs = t >> 7;
  __shared__ float smax[8][128];
  __shared__ float ssum[8][128];
  int per = n >> 3;
  const float* Xs = X + ((size_t)b * n + (size_t)rs * per) * Fd + f;
  float mx = -3.0e38f, sm = 0.f;
  for (int j = 0; j < per; j += 8) {
    float vv[8];
#pragma unroll
    for (int u = 0; u < 8; ++u) vv[u] = Xs[(size_t)(j + u) * Fd];
#pragma unroll
    for (int u = 0; u < 8; ++u) { mx = fmaxf(mx, vv[u]); sm += vv[u]; }
  }
  smax[rs][f] = mx; ssum[rs][f] = sm;
  __syncthreads();
  if (t < 128) {
    float m = smax[0][f], s = ssum[0][f];
#pragma unroll
    for (int q = 1; q < 8; ++q) { m = fmaxf(m, smax[q][f]); s += ssum[q][f]; }
    float a = fmaxf(m, 0.f);
    float m2 = fmaxf(s / (float)n, 0.f);
    if (init) { g[b * 384 + f] = a; g[b * 384 + 128 + f] = m2; }
    else      { g[b * 384 + f] += a; g[b * 384 + 128 + f] += m2; }
  }
}

// ---- A1 = softmax_row(leakyrelu(ar_i+ac_j) + bit(pi,pj)) + row stats ----
// Writes A as bf16 hi/lo planes (consumed conversion-free by k_mmf).
__global__ __launch_bounds__(256) void k_buildA_bit(const unsigned* __restrict__ adj,
    const int* __restrict__ perm, const float* __restrict__ ar, const float* __restrict__ ac,
    unsigned short* __restrict__ Ahi, unsigned short* __restrict__ Alo,
    float* __restrict__ disc, float* __restrict__ saO,
    float* __restrict__ disn, float* __restrict__ diagO) {
  int wid = threadIdx.x >> 6, lane = threadIdx.x & 63;
  int row = blockIdx.x * 4 + wid;      // [0, Bb*K1)
  int b = row >> 9, i = row & (K1 - 1);
  int pbase = b << 9;
  int pi = perm[pbase + i];
  float ari = ar[pbase + i];
  int j0 = lane * 8;
  float acv[8]; int pj[8];
  *(float4*)&acv[0] = *(const float4*)&ac[pbase + j0];
  *(float4*)&acv[4] = *(const float4*)&ac[pbase + j0 + 4];
  *(int4*)&pj[0] = *(const int4*)&perm[pbase + j0];
  *(int4*)&pj[4] = *(const int4*)&perm[pbase + j0 + 4];
  const unsigned* arow = adj + (size_t)((b << 10) + pi) * 32;
  float xv[8];
#pragma unroll
  for (int u = 0; u < 8; ++u) {
    float x = ari + acv[u];
    x = x > 0.f ? x : 0.2f * x;
    unsigned word = arow[pj[u] >> 5];
    xv[u] = x + (float)((word >> (pj[u] & 31)) & 1u);
  }
  float m = xv[0];
#pragma unroll
  for (int u = 1; u < 8; ++u) m = fmaxf(m, xv[u]);
  m = wred_max_all(m);
  float e[8], ls = 0.f;
#pragma unroll
  for (int u = 0; u < 8; ++u) { e[u] = expf(xv[u] - m); ls += e[u]; }
  float s = wred_sum_all(ls);
  float inv = 1.0f / s;
  float av[8]; float lsum = 0.f;
#pragma unroll
  for (int u = 0; u < 8; ++u) { av[u] = e[u] * inv; lsum += av[u]; }
  unsigned short hi[8], lo[8];
#pragma unroll
  for (int u = 0; u < 8; ++u) {
    hi[u] = bf16hi(av[u]);
    lo[u] = bf16hi(av[u] - bf2f(hi[u]));
  }
  uint4 ph, pl;
  ph.x = (unsigned)hi[0] | ((unsigned)hi[1] << 16);
  ph.y = (unsigned)hi[2] | ((unsigned)hi[3] << 16);
  ph.z = (unsigned)hi[4] | ((unsigned)hi[5] << 16);
  ph.w = (unsigned)hi[6] | ((unsigned)hi[7] << 16);
  pl.x = (unsigned)lo[0] | ((unsigned)lo[1] << 16);
  pl.y = (unsigned)lo[2] | ((unsigned)lo[3] << 16);
  pl.z = (unsigned)lo[4] | ((unsigned)lo[5] << 16);
  pl.w = (unsigned)lo[6] | ((unsigned)lo[7] << 16);
  *(uint4*)&Ahi[(size_t)row * K1 + j0] = ph;
  *(uint4*)&Alo[(size_t)row * K1 + j0] = pl;
  float rs = wred_sum_all(lsum);
  float dsel = av[i & 7];                 // uniform index
  float dval = __shfl(dsel, i >> 3, 64);
  if (lane == 0) {
    float sav = (dval == 0.f) ? 1.f : 0.f;
    float deg = rs + sav;
    disc[row] = deg > 0.f ? rsqrtf(deg) : 0.f;
    saO[row] = sav;
    float deg0 = rs - dval;
    disn[row] = deg0 > 0.f ? rsqrtf(deg0) : 0.f;
    diagO[row] = dval;
  }
}

// ---- A2 = softmax_row(leakyrelu(ar_i+ac_j) + A1[pi,pj]) + row stats ----
__global__ __launch_bounds__(256) void k_buildA_dense(
    const unsigned short* __restrict__ AprevHi, const unsigned short* __restrict__ AprevLo,
    const int* __restrict__ perm, const float* __restrict__ ar, const float* __restrict__ ac,
    unsigned short* __restrict__ Ahi, unsigned short* __restrict__ Alo,
    float* __restrict__ disc, float* __restrict__ saO,
    float* __restrict__ disn, float* __restrict__ diagO) {
  int wid = threadIdx.x >> 6, lane = threadIdx.x & 63;
  int row = blockIdx.x * 4 + wid;      // [0, Bb*K2)
  int b = row >> 8, i = row & (K2 - 1);
  int pbase = b << 8;
  int pi = perm[pbase + i];
  float ari = ar[pbase + i];
  int j0 = lane * 4;
  float acv[4]; int pj[4];
  *(float4*)&acv[0] = *(const float4*)&ac[pbase + j0];
  *(int4*)&pj[0] = *(const int4*)&perm[pbase + j0];
  size_t apbase = (size_t)((b << 9) + pi) * K1;
  float xv[4];
#pragma unroll
  for (int u = 0; u < 4; ++u) {
    float x = ari + acv[u];
    x = x > 0.f ? x : 0.2f * x;
    float aval = bf2f(AprevHi[apbase + pj[u]]) + bf2f(AprevLo[apbase + pj[u]]);
    xv[u] = x + aval;
  }
  float m = fmaxf(fmaxf(xv[0], xv[1]), fmaxf(xv[2], xv[3]));
  m = wred_max_all(m);
  float e[4], ls = 0.f;
#pragma unroll
  for (int u = 0; u < 4; ++u) { e[u] = expf(xv[u] - m); ls += e[u]; }
  float s = wred_sum_all(ls);
  float inv = 1.0f / s;
  float av[4]; float lsum = 0.f;
#pragma unroll
  for (int u = 0; u < 4; ++u) { av[u] = e[u] * inv; lsum += av[u]; }
  unsigned short hi[4], lo[4];
#pragma unroll
  for (int u = 0; u < 4; ++u) {
    hi[u] = bf16hi(av[u]);
    lo[u] = bf16hi(av[u] - bf2f(hi[u]));
  }
  uint2 ph, pl;
  ph.x = (unsigned)hi[0] | ((unsigned)hi[1] << 16);
  ph.y = (unsigned)hi[2] | ((unsigned)hi[3] << 16);
  pl.x = (unsigned)lo[0] | ((unsigned)lo[1] << 16);
  pl.y = (unsigned)lo[2] | ((unsigned)lo[3] << 16);
  *(uint2*)&Ahi[(size_t)row * K2 + j0] = ph;
  *(uint2*)&Alo[(size_t)row * K2 + j0] = pl;
  float rs = wred_sum_all(lsum);
  float dsel = av[i & 3];
  float dval = __shfl(dsel, i >> 2, 64);
  if (lane == 0) {
    float sav = (dval == 0.f) ? 1.f : 0.f;
    float deg = rs + sav;
    disc[row] = deg > 0.f ? rsqrtf(deg) : 0.f;
    saO[row] = sav;
    float deg0 = rs - dval;
    disn[row] = deg0 > 0.f ? rsqrtf(deg0) : 0.f;
    diagO[row] = dval;
  }
}

// ---- fused dense mm via 3xbf16-split MFMA, BM=64 BN=64, full-K ----
// A arrives pre-split as bf16 hi/lo planes (no in-kernel conversion).
// MODE 0 (conv): h = relu(dc*(acc + sa*dc*Y) + bias)
// MODE 1 (nis):  score2[row*2+ct] = col-tile partial of sum |hv - dn*(acc - diag*dn*hv)|
template <int MODE>
__global__ __launch_bounds__(512) void k_mmf(
    const unsigned short* __restrict__ Ahi, const unsigned short* __restrict__ Alo,
    const float* __restrict__ Y, const float* __restrict__ wrow,
    const float* __restrict__ aux, const float* __restrict__ bias,
    float* __restrict__ outp, int n) {
  __shared__ unsigned short AsHi[64 * 40], AsLo[64 * 40];
  __shared__ unsigned short YtHi[64 * 40], YtLo[64 * 40];
  int t = threadIdx.x;
  int tiles2 = (n >> 6) << 1;
  int bid = blockIdx.x;
  int c = bid & 7, q = bid >> 3;
  int g = c * 8 + q / tiles2;
  int rem = q % tiles2;
  int rt = rem >> 1, ct = rem & 1;
  const unsigned short* AbHi = Ahi + (size_t)g * n * n + (size_t)(rt * 64) * n;
  const unsigned short* AbLo = Alo + (size_t)g * n * n + (size_t)(rt * 64) * n;
  const float* Yb = Y + (size_t)g * n * Fd + ct * 64;
  const float* wb = wrow + (size_t)g * n;
  int sar = t >> 3, sak = (t & 7) << 2;
  int awoff = sar * 40 + ((sak >> 3) ^ ((sar >> 3) & 3)) * 8 + (sak & 4);
  int yc = t & 63, ykb = (t >> 6) & 3;
  int ywoff = yc * 40 + (ykb ^ ((yc >> 3) & 3)) * 8;
  int w = t >> 6, l = t & 63;
  int tr = w & 3, tcb = (w >> 2) << 1;
  int lr = l & 15, lg4 = l >> 4;
  int arow = 16 * tr + lr;
  int aroff = arow * 40 + ((lg4 ^ ((arow >> 3) & 3)) << 3);
  int col0 = 16 * tcb + lr, col1 = col0 + 16;
  int b0off = col0 * 40 + ((lg4 ^ ((col0 >> 3) & 3)) << 3);
  int b1off = col1 * 40 + ((lg4 ^ ((col1 >> 3) & 3)) << 3);
  float4v acc0 = {0.f, 0.f, 0.f, 0.f};
  float4v acc1 = {0.f, 0.f, 0.f, 0.f};
  for (int kb = 0; kb < n; kb += 32) {
    __syncthreads();
    {  // stage A hi/lo: direct u16x4 copies, no conversion
      uint2 ph = *(const uint2*)&AbHi[(size_t)sar * n + kb + sak];
      uint2 pl = *(const uint2*)&AbLo[(size_t)sar * n + kb + sak];
      *(uint2*)&AsHi[awoff] = ph;
      *(uint2*)&AsLo[awoff] = pl;
    }
    if (t < 256) {  // stage Yt hi/lo as col-strips (b128 writes)
      float vs[8];
      const float* yp = Yb + (size_t)(kb + ykb * 8) * Fd + yc;
      const float* wp = wb + kb + ykb * 8;
#pragma unroll
      for (int kk = 0; kk < 8; ++kk) vs[kk] = yp[(size_t)kk * Fd] * wp[kk];
      uint4 uh, ul;
      unsigned hu[4], lu[4];
#pragma unroll
      for (int kk = 0; kk < 4; ++kk) {
        unsigned short h0 = bf16hi(vs[2 * kk]);
        unsigned short l0 = bf16hi(vs[2 * kk] - bf2f(h0));
        unsigned short h1 = bf16hi(vs[2 * kk + 1]);
        unsigned short l1 = bf16hi(vs[2 * kk + 1] - bf2f(h1));
        hu[kk] = (unsigned)h0 | ((unsigned)h1 << 16);
        lu[kk] = (unsigned)l0 | ((unsigned)l1 << 16);
      }
      uh.x = hu[0]; uh.y = hu[1]; uh.z = hu[2]; uh.w = hu[3];
      ul.x = lu[0]; ul.y = lu[1]; ul.z = lu[2]; ul.w = lu[3];
      *(uint4*)&YtHi[ywoff] = uh;
      *(uint4*)&YtLo[ywoff] = ul;
    }
    __syncthreads();
    short8v ah = *(const short8v*)&AsHi[aroff];
    short8v al = *(const short8v*)&AsLo[aroff];
    short8v bh0 = *(const short8v*)&YtHi[b0off];
    short8v bl0 = *(const short8v*)&YtLo[b0off];
    short8v bh1 = *(const short8v*)&YtHi[b1off];
    short8v bl1 = *(const short8v*)&YtLo[b1off];
    acc0 = __builtin_amdgcn_mfma_f32_16x16x32_bf16(ah, bh0, acc0, 0, 0, 0);
    acc0 = __builtin_amdgcn_mfma_f32_16x16x32_bf16(ah, bl0, acc0, 0, 0, 0);
    acc0 = __builtin_amdgcn_mfma_f32_16x16x32_bf16(al, bh0, acc0, 0, 0, 0);
    acc1 = __builtin_amdgcn_mfma_f32_16x16x32_bf16(ah, bh1, acc1, 0, 0, 0);
    acc1 = __builtin_amdgcn_mfma_f32_16x16x32_bf16(ah, bl1, acc1, 0, 0, 0);
    acc1 = __builtin_amdgcn_mfma_f32_16x16x32_bf16(al, bh1, acc1, 0, 0, 0);
  }
  // epilogue: lane l holds D[row=(l>>4)*4+r][col=lr] of each tile
  int colg0 = ct * 64 + 16 * tcb + lr;
  int colg1 = colg0 + 16;
  if (MODE == 0) {
    float bv0 = bias[colg0], bv1 = bias[colg1];
#pragma unroll
    for (int r = 0; r < 4; ++r) {
      int row = rt * 64 + 16 * tr + ((l >> 4) << 2) + r;
      size_t R = (size_t)g * n + row;
      float dc = wb[row];
      float sv = aux[R] * dc;
      float y0 = Y[R * Fd + colg0];
      float y1 = Y[R * Fd + colg1];
      float o0 = fmaxf(dc * (acc0[r] + sv * y0) + bv0, 0.f);
      float o1 = fmaxf(dc * (acc1[r] + sv * y1) + bv1, 0.f);
      outp[R * Fd + colg0] = o0;
      outp[R * Fd + colg1] = o1;
    }
  } else {
#pragma unroll
    for (int r = 0; r < 4; ++r) {
      int row = rt * 64 + 16 * tr + ((l >> 4) << 2) + r;
      size_t R = (size_t)g * n + row;
      float dn = wb[row];
      float dg = aux[R] * dn;
      float h0 = Y[R * Fd + colg0];
      float h1 = Y[R * Fd + colg1];
      float p = fabsf(h0 - dn * (acc0[r] - dg * h0)) +
                fabsf(h1 - dn * (acc1[r] - dg * h1));
      p += __shfl_xor(p, 1, 64);
      p += __shfl_xor(p, 2, 64);
      p += __shfl_xor(p, 4, 64);
      p += __shfl_xor(p, 8, 64);
      if (lr == 0) outp[R * 2 + ct] = p;
    }
  }
}

// ---- fused head: xskew + mlp1 + mlp2 + mlp3 + log_softmax ----
__global__ __launch_bounds__(128) void k_head(const float* __restrict__ gin,
    const float* __restrict__ skew, const float* __restrict__ Wsk,
    const float* __restrict__ bsk, const float* __restrict__ Wl1,
    const float* __restrict__ bl1, const float* __restrict__ Wl2,
    const float* __restrict__ bl2, const float* __restrict__ Wl3,
    const float* __restrict__ bl3, float* __restrict__ out) {
  __shared__ float gl[384];
  __shared__ float t1s[128];
  __shared__ float t2s[64];
  __shared__ float lg[10];
  int b = blockIdx.x, f = threadIdx.x;
  gl[f] = gin[b * 384 + f];
  gl[128 + f] = gin[b * 384 + 128 + f];
  float acc = bsk[f];
  for (int s = 0; s < 64; ++s) acc += skew[b * 64 + s] * Wsk[s * Fd + f];
  gl[256 + f] = fmaxf(acc, 0.f);
  __syncthreads();
  acc = bl1[f];
  for (int s = 0; s < 384; ++s) acc += gl[s] * Wl1[s * 128 + f];
  t1s[f] = fmaxf(acc, 0.f);
  __syncthreads();
  if (f < 64) {
    acc = bl2[f];
    for (int s = 0; s < 128; ++s) acc += t1s[s] * Wl2[s * 64 + f];
    t2s[f] = fmaxf(acc, 0.f);
  }
  __syncthreads();
  if (f < 10) {
    acc = bl3[f];
    for (int s = 0; s < 64; ++s) acc += t2s[s] * Wl3[s * 10 + f];
    lg[f] = acc;
  }
  __syncthreads();
  if (f == 0) {
    float m = lg[0];
    for (int c = 1; c < 10; ++c) m = fmaxf(m, lg[c]);
    float s = 0.f;
    for (int c = 0; c < 10; ++c) s += expf(lg[c] - m);
    float l = logf(s);
    for (int c = 0; c < 10; ++c) out[b * 10 + c] = lg[c] - m - l;
  }
}

extern "C" void kernel_launch(void* const* d_in, const int* in_sizes, int n_in,
                              void* d_out, int out_size, void* d_ws, size_t ws_size,
                              hipStream_t stream) {
  const float* x    = (const float*)d_in[0];
  const int*   src  = (const int*)d_in[1];
  const int*   dst  = (const int*)d_in[2];
  const float* skew = (const float*)d_in[3];
  const float* W1   = (const float*)d_in[4];
  const float* b1   = (const float*)d_in[5];
  const float* W2   = (const float*)d_in[6];
  const float* b2   = (const float*)d_in[7];
  const float* W3   = (const float*)d_in[8];
  const float* b3   = (const float*)d_in[9];
  const float* att1 = (const float*)d_in[10];
  const float* att2 = (const float*)d_in[11];
  const float* Wsk  = (const float*)d_in[12];
  const float* bsk  = (const float*)d_in[13];
  const float* Wl1  = (const float*)d_in[14];
  const float* bl1  = (const float*)d_in[15];
  const float* Wl2  = (const float*)d_in[16];
  const float* bl2  = (const float*)d_in[17];
  const float* Wl3  = (const float*)d_in[18];
  const float* bl3  = (const float*)d_in[19];
  float* out = (float*)d_out;

  char* base = (char*)d_ws;
  size_t off = 0;
  auto alloc = [&](size_t bytes) -> void* {
    void* p = base + off;
    off += (bytes + 255) & ~(size_t)255;
    return p;
  };

  unsigned* adj = (unsigned*)alloc((size_t)Bb * N0 * 32 * 4);        // 8 MB
  float* dis0 = (float*)alloc((size_t)Bb * N0 * 4);
  float* dis1 = (float*)alloc((size_t)Bb * N0 * 4);
  int*   degv = (int*)alloc((size_t)Bb * N0 * 4);
  float* bigA = (float*)alloc((size_t)64 * 1024 * 1024);             // 64 MB multi-use
  float* XW  = bigA;                                                  // [B,1024,128]
  float* h1  = bigA + (size_t)Bb * N0 * Fd;                           // [B,1024,128]
  unsigned short* A1hi = (unsigned short*)bigA;                       // 32 MB (after XW/h1 dead)
  unsigned short* A1lo = (unsigned short*)bigA + (size_t)Bb * K1 * K1;// 32 MB
  float* XW3 = bigA;                                                  // [B,256,128] (after A1 dead)
  float* h3  = bigA + (size_t)Bb * K2 * Fd;                           // [B,256,128]
  float* partial = (float*)alloc((size_t)Bb * N0 * 8 * 4);            // 2 MB; also score2
  int*   perm1 = (int*)alloc((size_t)Bb * K1 * 4);
  float* Xp1 = (float*)alloc((size_t)Bb * K1 * Fd * 4);               // later reused as A2 planes
  unsigned short* A2hi = (unsigned short*)Xp1;                        // 8 MB
  unsigned short* A2lo = (unsigned short*)Xp1 + (size_t)Bb * K2 * K2; // 8 MB
  float* ar1 = (float*)alloc((size_t)Bb * K1 * 4);
  float* ac1 = (float*)alloc((size_t)Bb * K1 * 4);
  float* disc2 = (float*)alloc((size_t)Bb * K1 * 4);
  float* sa2   = (float*)alloc((size_t)Bb * K1 * 4);
  float* disn2 = (float*)alloc((size_t)Bb * K1 * 4);
  float* diag2 = (float*)alloc((size_t)Bb * K1 * 4);
  float* XW2 = (float*)alloc((size_t)Bb * K1 * Fd * 4);               // 16 MB
  float* h2  = (float*)alloc((size_t)Bb * K1 * Fd * 4);               // 16 MB
  int*   perm2 = (int*)alloc((size_t)Bb * K2 * 4);
  float* Xp2 = (float*)alloc((size_t)Bb * K2 * Fd * 4);
  float* ar2 = (float*)alloc((size_t)Bb * K2 * 4);
  float* ac2 = (float*)alloc((size_t)Bb * K2 * 4);
  float* disc3 = (float*)alloc((size_t)Bb * K2 * 4);
  float* sa3   = (float*)alloc((size_t)Bb * K2 * 4);
  float* disn3 = (float*)alloc((size_t)Bb * K2 * 4);
  float* diag3 = (float*)alloc((size_t)Bb * K2 * 4);
  float* g  = (float*)alloc((size_t)Bb * 384 * 4);
  // nbr [B*N0][128] u16 = 16 MB; overlays XW2 (dead until stage-2 gemm)
  unsigned short* nbr = (unsigned short*)XW2;
  (void)ws_size; (void)in_sizes; (void)n_in; (void)out_size;

  // stage 1: fused graph build, MFMA gemm, fused conv+nis
  k_graph<<<Bb * 4, 1024, 0, stream>>>(src, dst, adj, nbr, degv, dis0, dis1);
  k_gemmm<<<Bb * N0 / 64, 512, 0, stream>>>(x, W1, XW);
  k_convnis<<<Bb * 8, 1024, 0, stream>>>(nbr, degv, XW, dis0, dis1, b1, h1, partial);
  k_topk<<<Bb, N0, 0, stream>>>(partial, perm1, N0, K1, 8);
  k_gather<<<Bb * K1, 128, 0, stream>>>(h1, perm1, att1, Xp1, ar1, ac1, N0, K1);
  k_readout<<<Bb, 1024, 0, stream>>>(Xp1, K1, g, 1);
  k_buildA_bit<<<Bb * K1 / 4, 256, 0, stream>>>(adj, perm1, ar1, ac1, A1hi, A1lo,
                                                disc2, sa2, disn2, diag2);  // overwrites XW/h1

  // stage 2: dense A1 (MFMA mm with pre-split A planes, fused epilogues)
  k_gemmm<<<Bb * K1 / 64, 512, 0, stream>>>(Xp1, W2, XW2);
  k_mmf<0><<<Bb * (K1 / 64) * 2, 512, 0, stream>>>(A1hi, A1lo, XW2, disc2, sa2, b2, h2, K1);
  k_mmf<1><<<Bb * (K1 / 64) * 2, 512, 0, stream>>>(A1hi, A1lo, h2, disn2, diag2, nullptr, partial, K1);
  k_topk<<<Bb, K1, 0, stream>>>(partial, perm2, K1, K2, 2);
  k_gather<<<Bb * K2, 128, 0, stream>>>(h2, perm2, att2, Xp2, ar2, ac2, K1, K2);
  k_readout<<<Bb, 1024, 0, stream>>>(Xp2, K2, g, 0);
  k_buildA_dense<<<Bb * K2 / 4, 256, 0, stream>>>(A1hi, A1lo, perm2, ar2, ac2,
                                                  A2hi, A2lo, disc3, sa3, disn3, diag3);

  // stage 3: dense A2
  k_gemmm<<<Bb * K2 / 64, 512, 0, stream>>>(Xp2, W3, XW3);             // overwrites A1 region
  k_mmf<0><<<Bb * (K2 / 64) * 2, 512, 0, stream>>>(A2hi, A2lo, XW3, disc3, sa3, b3, h3, K2);
  k_readout<<<Bb, 1024, 0, stream>>>(h3, K2, g, 0);

  // fused head
  k_head<<<Bb, 128, 0, stream>>>(g, skew, Wsk, bsk, Wl1, bl1, Wl2, bl2, Wl3, bl3, out);
}